// Round 4
// baseline (424.098 us; speedup 1.0000x reference)
//
#include <hip/hip_runtime.h>
#include <cfloat>
#include <cstddef>

// Problem constants
#define NROWS 65536          // 64 * 32 * 32 flattened rows
#define KCB   1024           // codebook entries
#define DDIM  64             // embedding dim
#define QSIZE 4194304        // 64*64*32*32
#define POFF  (1 + QSIZE)    // perplexity position in d_out
#define EOFF  (2 + QSIZE)    // encodings start in d_out
#define NQBLK 16384          // k_quant grid size
#define TAU   4.0e-3f        // phase-A certainty margin (fp16-E gap err 5sigma ~1.7e-3)

// ws layout:
//   [0, 262144)          idx      int32[65536]
//   [262144, 266240)     counts   int32[1024]
//   [266240, 270336)     esq      float[1024]
//   [270336, 335872)     partials float[16384]
//   [335872, 466944)     Eh       fp16[65536]   (codebook, fp16 RTN)
//   [466944, 471040)     flagcnt  int32[1024]
//   [471040, 733184)     flagrows int32[1024*64]

typedef _Float16 f16x8 __attribute__((ext_vector_type(8)));
typedef float floatx4 __attribute__((ext_vector_type(4)));

// ---------------------------------------------------------------------------
// Kernel 0: ||e_k||^2 (fp64 sum of fp32-rounded squares) + fp16 cast of E
// ---------------------------------------------------------------------------
__global__ void k_esq(const float* __restrict__ E, float* __restrict__ esq,
                      _Float16* __restrict__ Eh) {
    int k = blockIdx.x * 256 + threadIdx.x;
    if (k < KCB) {
        double s = 0.0;
        #pragma unroll
        for (int d = 0; d < DDIM; ++d) {
            float v = E[(k << 6) + d];
            float sq = v * v;
            s += (double)sq;
            Eh[(k << 6) + d] = (_Float16)v;
        }
        esq[k] = (float)s;
    }
}

// ---------------------------------------------------------------------------
// Phase A: approx distances via fp16 MFMA. x split hi/lo fp16 (x error ~2^-22),
// E plain fp16 (dominant error, rms ~2.4e-4 on dist). Track per-row top-2 of
// (esq_k - 2*dot); rows with gap <= TAU go to exact re-check.
// Layouts (verified by R3 pass): A[m=lane&15][k=quad*8+j], B[n=lane&15][k=quad*8+j],
// D: row(m)=quad*4+reg, col(n)=lane&15.
// 4 chunks of 256 k; per kt-tile: 2 ds_read_b128 + 4 MFMA. Lean register set +
// launch_bounds(256,4) to guarantee no spill (R3's 6-pass full-unroll version
// blew VGPRs: 148 us chain).
// ---------------------------------------------------------------------------
__launch_bounds__(256, 4)
__global__ void k_amin_mfma(const float* __restrict__ x,
                            const _Float16* __restrict__ Eh,
                            const float* __restrict__ esq,
                            int* __restrict__ out_idx,
                            int* __restrict__ flagcnt,
                            int* __restrict__ flagrows) {
    // 256 k-rows per chunk, stride 72 halves (144 B = 9*16 -> 16B-aligned,
    // b128 bank-group distribution uniform -> conflict-free)
    __shared__ _Float16 es[256 * 72];
    __shared__ float eqs[256];
    __shared__ int fl_cnt;
    __shared__ int fl_list[64];

    const int tid  = threadIdx.x;
    const int bb   = blockIdx.x;
    const int n0   = bb * 64;
    const int b    = n0 >> 10;
    const int p0   = n0 & 1023;
    const int wid  = tid >> 6;
    const int lane = tid & 63;
    const int li   = lane & 15;
    const int quad = lane >> 4;

    if (tid == 0) fl_cnt = 0;

    // A-frags direct from global (coalesced in 16-lane runs), fp16 hi/lo split
    f16x8 xh0, xl0, xh1, xl1;
    const int colbase = p0 + wid * 16 + li;
    #pragma unroll
    for (int j = 0; j < 8; ++j) {
        float v0 = x[(size_t)(b * 64 + quad * 8 + j) * 1024 + colbase];
        float v1 = x[(size_t)(b * 64 + 32 + quad * 8 + j) * 1024 + colbase];
        _Float16 h0 = (_Float16)v0;
        _Float16 h1 = (_Float16)v1;
        xh0[j] = h0; xl0[j] = (_Float16)(v0 - (float)h0);
        xh1[j] = h1; xl1[j] = (_Float16)(v1 - (float)h1);
    }

    float b1[4], b2[4]; int i1[4];
    #pragma unroll
    for (int r = 0; r < 4; ++r) { b1[r] = FLT_MAX; b2[r] = FLT_MAX; i1[r] = 0; }

    for (int c = 0; c < 4; ++c) {
        __syncthreads();   // protect es reuse across chunks (also covers fl_cnt init)
        // stage 256 codebook rows (fp16) + their esq
        for (int u = tid; u < 2048; u += 256) {
            int kl = u >> 3, d8 = u & 7;
            const size_t src = ((size_t)(c * 256 + kl) << 6) + d8 * 8;
            *(uint4*)&es[kl * 72 + d8 * 8] = *(const uint4*)&Eh[src];
        }
        eqs[tid] = esq[c * 256 + tid];
        __syncthreads();

        #pragma unroll 4
        for (int kt = 0; kt < 16; ++kt) {
            const int krow = (kt * 16 + li) * 72 + quad * 8;
            const f16x8 bh0 = *(const f16x8*)&es[krow];
            const f16x8 bh1 = *(const f16x8*)&es[krow + 32];
            floatx4 cc = {0.f, 0.f, 0.f, 0.f};
            cc = __builtin_amdgcn_mfma_f32_16x16x32_f16(xh0, bh0, cc, 0, 0, 0);
            cc = __builtin_amdgcn_mfma_f32_16x16x32_f16(xh1, bh1, cc, 0, 0, 0);
            cc = __builtin_amdgcn_mfma_f32_16x16x32_f16(xl0, bh0, cc, 0, 0, 0);
            cc = __builtin_amdgcn_mfma_f32_16x16x32_f16(xl1, bh1, cc, 0, 0, 0);
            const float eq = eqs[kt * 16 + li];
            const int kglob = c * 256 + kt * 16 + li;
            #pragma unroll
            for (int r = 0; r < 4; ++r) {
                float dv = fmaf(-2.0f, cc[r], eq);
                bool lt = dv < b1[r];
                b2[r] = lt ? b1[r] : fminf(b2[r], dv);
                i1[r] = lt ? kglob : i1[r];
                b1[r] = lt ? dv : b1[r];
            }
        }
    }

    // merge top-2 across the 16 lanes of each quad-group
    #pragma unroll
    for (int r = 0; r < 4; ++r) {
        float v1v = b1[r]; int vi = i1[r]; float v2v = b2[r];
        #pragma unroll
        for (int off = 8; off > 0; off >>= 1) {
            float o1 = __shfl_xor(v1v, off, 16);
            int   oi = __shfl_xor(vi,  off, 16);
            float o2 = __shfl_xor(v2v, off, 16);
            float nb2 = fminf(fminf(v2v, o2), fmaxf(v1v, o1));
            bool take = (o1 < v1v) || (o1 == v1v && oi < vi);
            v1v = take ? o1 : v1v;
            vi  = take ? oi : vi;
            v2v = nb2;
        }
        b1[r] = v1v; i1[r] = vi; b2[r] = v2v;
    }

    if (li == 0) {
        const int m0 = n0 + wid * 16;
        #pragma unroll
        for (int r = 0; r < 4; ++r) {
            int row = m0 + quad * 4 + r;
            out_idx[row] = i1[r];
            if (b2[r] - b1[r] <= TAU) {
                int pos = atomicAdd(&fl_cnt, 1);
                fl_list[pos] = row;
            }
        }
    }
    __syncthreads();
    if (tid == 0) flagcnt[bb] = fl_cnt;
    for (int u = tid; u < fl_cnt; u += 256) flagrows[bb * 64 + u] = fl_list[u];
}

// ---------------------------------------------------------------------------
// Phase B: exact re-check of flagged rows, R1's fp64-chunk method
// (empirically matches numpy argmin over all 65536 rows, 2 passes).
// ---------------------------------------------------------------------------
__launch_bounds__(256)
__global__ void k_amin_exact(const float* __restrict__ x, const float* __restrict__ E,
                             const float* __restrict__ esq,
                             const int* __restrict__ flagcnt, const int* __restrict__ flagrows,
                             int* __restrict__ out_idx) {
    const int bb = blockIdx.x;
    const int cnt = flagcnt[bb];
    if (cnt == 0) return;
    __shared__ float xr[64];
    __shared__ float rbest[4]; __shared__ int ribest[4];
    const int tid = threadIdx.x;
    for (int fi = 0; fi < cnt; ++fi) {
        const int row = flagrows[bb * 64 + fi];
        const int b = row >> 10, p = row & 1023;
        __syncthreads();
        if (tid < 64) xr[tid] = x[(size_t)(b * 64 + tid) * 1024 + p];
        __syncthreads();
        double As = 0.0;
        #pragma unroll
        for (int d = 0; d < 64; ++d) { float v = xr[d]; float sq = v * v; As += (double)sq; }
        float A = (float)As;
        float bd = FLT_MAX; int bi = 0;
        #pragma unroll
        for (int kk = 0; kk < 4; ++kk) {
            int k = tid * 4 + kk;
            const float* Ek = E + ((size_t)k << 6);
            double acc = 0.0;
            #pragma unroll
            for (int ch = 0; ch < 8; ++ch) {
                float a32 = 0.f;
                #pragma unroll
                for (int dd = 0; dd < 8; ++dd) {
                    int d = ch * 8 + dd;
                    a32 = fmaf(xr[d], Ek[d], a32);
                }
                acc += (double)a32;
            }
            float dist = (A - 2.0f * (float)acc) + esq[k];
            if (dist < bd) { bd = dist; bi = k; }      // ascending k -> lowest-idx ties
        }
        #pragma unroll
        for (int off = 32; off > 0; off >>= 1) {
            float od = __shfl_down(bd, off, 64);
            int   oi = __shfl_down(bi, off, 64);
            if (od < bd || (od == bd && oi < bi)) { bd = od; bi = oi; }
        }
        if ((tid & 63) == 0) { rbest[tid >> 6] = bd; ribest[tid >> 6] = bi; }
        __syncthreads();
        if (tid == 0) {
            float fb = rbest[0]; int fk = ribest[0];
            for (int wq = 1; wq < 4; ++wq)
                if (rbest[wq] < fb || (rbest[wq] == fb && ribest[wq] < fk)) { fb = rbest[wq]; fk = ribest[wq]; }
            out_idx[row] = fk;
        }
    }
}

// ---------------------------------------------------------------------------
// Kernel 2: quantized output (NCHW) + per-block partial loss sum (no atomics)
// ---------------------------------------------------------------------------
__global__ void k_quant(const float* __restrict__ x, const float* __restrict__ E,
                        const int* __restrict__ idx, float* __restrict__ out_q,
                        float* __restrict__ partials) {
    int gid = blockIdx.x * 256 + threadIdx.x;
    int p = gid & 1023;
    int c = (gid >> 10) & 63;
    int b = gid >> 16;
    int n = (b << 10) | p;
    int id = idx[n];
    float q  = E[(id << 6) + c];
    float xv = x[gid];
    out_q[gid] = q;
    float df = q - xv;
    float val = df * df;
    #pragma unroll
    for (int off = 32; off > 0; off >>= 1) val += __shfl_down(val, off, 64);
    __shared__ float wsum[4];
    int lane = threadIdx.x & 63, w = threadIdx.x >> 6;
    if (lane == 0) wsum[w] = val;
    __syncthreads();
    if (threadIdx.x == 0)
        partials[blockIdx.x] = wsum[0] + wsum[1] + wsum[2] + wsum[3];
}

// ---------------------------------------------------------------------------
// Kernel 3: histogram of indices (LDS privatized)
// ---------------------------------------------------------------------------
__global__ void k_hist(const int* __restrict__ idx, int* __restrict__ counts) {
    __shared__ int h[KCB];
    for (int i = threadIdx.x; i < KCB; i += 256) h[i] = 0;
    __syncthreads();
    for (int n = blockIdx.x * 256 + threadIdx.x; n < NROWS; n += gridDim.x * 256)
        atomicAdd(&h[idx[n]], 1);
    __syncthreads();
    for (int i = threadIdx.x; i < KCB; i += 256)
        if (h[i]) atomicAdd(&counts[i], h[i]);
}

// ---------------------------------------------------------------------------
// Kernel 4: finalize loss (fp64 partial reduce) + perplexity
// ---------------------------------------------------------------------------
__global__ void k_final(const int* __restrict__ counts, const float* __restrict__ partials,
                        float* __restrict__ out) {
    int tid = threadIdx.x;                        // 1024 threads
    double ls = 0.0;
    for (int i = tid; i < NQBLK; i += 1024) ls += (double)partials[i];
    float p = (float)counts[tid] / 65536.0f;
    float v = p * logf(p + 1e-10f);
    #pragma unroll
    for (int off = 32; off > 0; off >>= 1) {
        v  += __shfl_down(v, off, 64);
        ls += __shfl_down(ls, off, 64);
    }
    __shared__ float  sb[16];
    __shared__ double lb[16];
    int lane = tid & 63, w = tid >> 6;
    if (lane == 0) { sb[w] = v; lb[w] = ls; }
    __syncthreads();
    if (tid == 0) {
        float s = 0.0f; double L = 0.0;
        #pragma unroll
        for (int k = 0; k < 16; ++k) { s += sb[k]; L += lb[k]; }
        out[POFF] = expf(-s);
        out[0] = (float)(1.25 * L / 4194304.0);
    }
}

// ---------------------------------------------------------------------------
// Kernel 5: one-hot encodings, full-row write (EOFF is 8B-aligned -> float2)
// ---------------------------------------------------------------------------
__global__ void k_enc(const int* __restrict__ idx, float* __restrict__ enc) {
    int n = blockIdx.x;
    int id = idx[n];
    int t = threadIdx.x;
    size_t base = (size_t)n * KCB;
    int p0 = t * 2, p1 = t * 2 + 512;
    float2 a, bb;
    a.x  = (id == p0)     ? 1.0f : 0.0f;
    a.y  = (id == p0 + 1) ? 1.0f : 0.0f;
    bb.x = (id == p1)     ? 1.0f : 0.0f;
    bb.y = (id == p1 + 1) ? 1.0f : 0.0f;
    *(float2*)(enc + base + p0) = a;
    *(float2*)(enc + base + p1) = bb;
}

extern "C" void kernel_launch(void* const* d_in, const int* in_sizes, int n_in,
                              void* d_out, int out_size, void* d_ws, size_t ws_size,
                              hipStream_t stream) {
    const float* x = (const float*)d_in[0];   // [64,64,32,32] NCHW fp32
    const float* E = (const float*)d_in[1];   // [1024,64] fp32
    float* out = (float*)d_out;
    char* ws = (char*)d_ws;
    int*      idxp     = (int*)ws;
    int*      counts   = (int*)(ws + 262144);
    float*    esq      = (float*)(ws + 266240);
    float*    partials = (float*)(ws + 270336);
    _Float16* Ehw      = (_Float16*)(ws + 335872);
    int*      flagcnt  = (int*)(ws + 466944);
    int*      flagrows = (int*)(ws + 471040);

    hipMemsetAsync(ws + 262144, 0, 4096, stream);   // counts only

    k_esq       <<<4,     256, 0, stream>>>(E, esq, Ehw);
    k_amin_mfma <<<1024,  256, 0, stream>>>(x, Ehw, esq, idxp, flagcnt, flagrows);
    k_amin_exact<<<1024,  256, 0, stream>>>(x, E, esq, flagcnt, flagrows, idxp);
    k_quant     <<<NQBLK, 256, 0, stream>>>(x, E, idxp, out + 1, partials);
    k_hist      <<<64,    256, 0, stream>>>(idxp, counts);
    k_final     <<<1,    1024, 0, stream>>>(counts, partials, out);
    k_enc       <<<65536, 256, 0, stream>>>(idxp, out + (size_t)EOFF);
}